// Round 13
// baseline (46.302 us; speedup 1.0000x reference)
//
#include <hip/hip_runtime.h>
#include <math.h>

namespace {
constexpr int B = 4, N = 4, C = 64, H = 128, W = 256, L = 5;
constexpr int HW = H * W;
constexpr int WAVES = 8;          // waves per block
constexpr int CPW = C / WAVES;    // channels per wave = 8
constexpr int NXCD = 8;
constexpr int NWG = B * (W / 64) * H;   // 2048, divisible by 8
}

// 8-byte pair load with only 4-byte alignment guarantee (x-taps are adjacent).
typedef float f2v __attribute__((ext_vector_type(2), aligned(4)));

__global__ __launch_bounds__(512, 4) void atten_comm_kernel(
    const float* __restrict__ x,    // (B*N, C, H, W)
    const float* __restrict__ P,    // (B, L, L, 4, 4)
    float* __restrict__ out)        // (B, C, H, W)
{
    __shared__ float sred[WAVES][N][64];

    // XCD-aware swizzle (T1): dispatch round-robins wg->XCD by (g % 8).
    // Give each XCD a contiguous orig-id chunk so consecutive-h blocks
    // (which share warped source rows) co-reside in one XCD's L2.
    const int g    = (int)blockIdx.x;
    const int orig = (g & (NXCD - 1)) * (NWG / NXCD) + (g >> 3);
    const int h    = orig & (H - 1);          // h fastest
    const int wc   = (orig >> 7) & 3;         // then w-chunk
    const int b    = orig >> 9;               // then batch

    const int lane = (int)(threadIdx.x & 63);
    const int wv   = (int)(threadIdx.x >> 6);
    const int w    = (wc << 6) + lane;

    // normalized grid coords (align_corners=True)
    const float gx = -1.0f + (2.0f / (float)(W - 1)) * (float)w;
    const float gy = -1.0f + (2.0f / (float)(H - 1)) * (float)h;

    const float* basep[N];
    int   voff0[N], voff1[N];               // element offsets of the two row pairs
    float u0x[N], u0y[N], u1x[N], u1y[N];   // folded bilinear+boundary weights

#pragma unroll
    for (int n = 0; n < N; ++n) {
        // P[b, 0, n, r, c]; strides: b:L*L*16, i:L*16, j:16, r:4, c:1
        const float* p = P + ((size_t)b * L * L + (size_t)n) * 16;
        const float a  = p[0];
        const float bb = p[1] * ((float)H / (float)W);
        const float cc = p[3] * (2.0f / (4.0f * 0.4f * (float)W));
        const float d  = p[4] * ((float)W / (float)H);
        const float e  = p[5];
        const float ff = p[7] * (2.0f / (4.0f * 0.4f * (float)H));

        const float g0 = a * gx + bb * gy + cc;
        const float g1 = d * gx + e * gy + ff;
        const float ix = (g0 + 1.0f) * (0.5f * (float)(W - 1));
        const float iy = (g1 + 1.0f) * (0.5f * (float)(H - 1));

        const float fx0 = floorf(ix);
        const float fy0 = floorf(iy);
        const int x0 = (int)fx0, y0 = (int)fy0;
        const int y1 = y0 + 1;
        const float wx = ix - fx0;
        const float wy = iy - fy0;

        // x-pair: load (xa, xa+1); both x-taps live in this window with
        // boundary cases folded into (ux, uy):
        const int   xa   = min(max(x0, 0), W - 2);
        const float wx0v = (1.0f - wx) * ((x0 >= 0 && x0 < W) ? 1.0f : 0.0f);
        const float wx1v = wx * ((x0 + 1 >= 0 && x0 + 1 < W) ? 1.0f : 0.0f);
        // interior: (wx0v, wx1v); x0==-1: taps shift left -> (wx1v, 0);
        // x0==W-1: taps shift right -> (0, wx0v); fully OOB collapses to 0.
        const float ux = (x0 < 0) ? wx1v : ((x0 > W - 2) ? 0.0f : wx0v);
        const float uy = (x0 < 0) ? 0.0f : ((x0 > W - 2) ? wx0v : wx1v);

        const int yc0 = min(max(y0, 0), H - 1);
        const int yc1 = min(max(y1, 0), H - 1);
        const float wyv0 = (1.0f - wy) * ((y0 >= 0 && y0 < H) ? 1.0f : 0.0f);
        const float wyv1 = wy * ((y1 >= 0 && y1 < H) ? 1.0f : 0.0f);

        u0x[n] = ux * wyv0;  u0y[n] = uy * wyv0;
        u1x[n] = ux * wyv1;  u1y[n] = uy * wyv1;
        voff0[n] = yc0 * W + xa;
        voff1[n] = yc1 * W + xa;

        basep[n] = x + ((size_t)(b * N + n) * C + (size_t)(wv * CPW)) * HW;
    }

    // ---- gather: 8 pair-loads per channel issued before the FMAs ----
    float f[N][CPW];
#pragma unroll
    for (int cc = 0; cc < CPW; ++cc) {
        f2v t0[N], t1[N];
#pragma unroll
        for (int n = 0; n < N; ++n) {
            const float* pl = basep[n] + (size_t)cc * HW;
            t0[n] = *(const f2v*)(pl + voff0[n]);
            t1[n] = *(const f2v*)(pl + voff1[n]);
        }
#pragma unroll
        for (int n = 0; n < N; ++n) {
            f[n][cc] = u0x[n] * t0[n].x + u0y[n] * t0[n].y
                     + u1x[n] * t1[n].x + u1y[n] * t1[n].y;
        }
    }

    // ---- partial scores over this wave's channels ----
    float s[N] = {0.f, 0.f, 0.f, 0.f};
#pragma unroll
    for (int cc = 0; cc < CPW; ++cc) {
        const float q = f[0][cc];
#pragma unroll
        for (int n = 0; n < N; ++n) s[n] += q * f[n][cc];
    }

    // ---- cross-wave reduction via LDS (lane-stride-1, conflict-free) ----
#pragma unroll
    for (int n = 0; n < N; ++n) sred[wv][n][lane] = s[n];
    __syncthreads();

    float st[N];
#pragma unroll
    for (int n = 0; n < N; ++n) {
        float acc = 0.f;
#pragma unroll
        for (int v = 0; v < WAVES; ++v) acc += sred[v][n][lane];
        st[n] = acc;
    }

    const float scale = 0.125f;  // 1/sqrt(64)
    const float s0 = st[0] * scale, s1 = st[1] * scale;
    const float s2 = st[2] * scale, s3 = st[3] * scale;
    const float m  = fmaxf(fmaxf(s0, s1), fmaxf(s2, s3));
    const float e0 = expf(s0 - m);
    const float e1 = expf(s1 - m);
    const float e2 = expf(s2 - m);
    const float e3 = expf(s3 - m);
    const float inv = 1.0f / (e0 + e1 + e2 + e3);
    const float attn[N] = {e0 * inv, e1 * inv, e2 * inv, e3 * inv};

    // ---- context from registers + non-temporal coalesced store ----
    // out is write-once / never re-read by this kernel: nt keeps the 33 MB
    // write stream from evicting x out of the Infinity Cache between replays.
    float* op = out + ((size_t)b * C + (size_t)(wv * CPW)) * HW
                    + (size_t)h * W + (size_t)w;
#pragma unroll
    for (int cc = 0; cc < CPW; ++cc) {
        float ctx = 0.f;
#pragma unroll
        for (int n = 0; n < N; ++n) ctx += attn[n] * f[n][cc];
        __builtin_nontemporal_store(ctx, &op[(size_t)cc * HW]);
    }
}

extern "C" void kernel_launch(void* const* d_in, const int* in_sizes, int n_in,
                              void* d_out, int out_size, void* d_ws, size_t ws_size,
                              hipStream_t stream) {
    const float* x  = (const float*)d_in[0];
    const float* P  = (const float*)d_in[1];
    float* out = (float*)d_out;

    dim3 block(512, 1, 1);
    dim3 grid(NWG, 1, 1);  // 2048 blocks, 1D, XCD-swizzled in-kernel
    hipLaunchKernelGGL(atten_comm_kernel, grid, block, 0, stream, x, P, out);
}

// Round 14
// 45.587 us; speedup vs baseline: 1.0157x; 1.0157x over previous
//
#include <hip/hip_runtime.h>
#include <math.h>

namespace {
constexpr int B = 4, N = 4, C = 64, H = 128, W = 256, L = 5;
constexpr int HW = H * W;
constexpr int WAVES = 8;          // waves per block
constexpr int CPW = C / WAVES;    // channels per wave = 8
constexpr int NXCD = 8;
constexpr int NWG = B * (W / 64) * H;   // 2048, divisible by 8
}

// 8-byte pair load with only 4-byte alignment guarantee (x-taps are adjacent).
typedef float f2v __attribute__((ext_vector_type(2), aligned(4)));

__global__ __launch_bounds__(512, 3) void atten_comm_kernel(
    const float* __restrict__ x,    // (B*N, C, H, W)
    const float* __restrict__ P,    // (B, L, L, 4, 4)
    float* __restrict__ out)        // (B, C, H, W)
{
    __shared__ float sred[WAVES][N][64];

    // XCD-aware swizzle (T1): dispatch round-robins wg->XCD by (g % 8).
    // Give each XCD a contiguous orig-id chunk so consecutive-h blocks
    // (which share warped source rows) co-reside in one XCD's L2.
    const int g    = (int)blockIdx.x;
    const int orig = (g & (NXCD - 1)) * (NWG / NXCD) + (g >> 3);
    const int h    = orig & (H - 1);          // h fastest
    const int wc   = (orig >> 7) & 3;         // then w-chunk
    const int b    = orig >> 9;               // then batch

    const int lane = (int)(threadIdx.x & 63);
    const int wv   = (int)(threadIdx.x >> 6);
    const int w    = (wc << 6) + lane;

    // normalized grid coords (align_corners=True)
    const float gx = -1.0f + (2.0f / (float)(W - 1)) * (float)w;
    const float gy = -1.0f + (2.0f / (float)(H - 1)) * (float)h;

    const float* basep[N];
    int   voff0[N], voff1[N];               // element offsets of the two row pairs
    float u0x[N], u0y[N], u1x[N], u1y[N];   // folded bilinear+boundary weights

#pragma unroll
    for (int n = 0; n < N; ++n) {
        // P[b, 0, n, r, c]; strides: b:L*L*16, i:L*16, j:16, r:4, c:1
        const float* p = P + ((size_t)b * L * L + (size_t)n) * 16;
        const float a  = p[0];
        const float bb = p[1] * ((float)H / (float)W);
        const float cc = p[3] * (2.0f / (4.0f * 0.4f * (float)W));
        const float d  = p[4] * ((float)W / (float)H);
        const float e  = p[5];
        const float ff = p[7] * (2.0f / (4.0f * 0.4f * (float)H));

        const float g0 = a * gx + bb * gy + cc;
        const float g1 = d * gx + e * gy + ff;
        const float ix = (g0 + 1.0f) * (0.5f * (float)(W - 1));
        const float iy = (g1 + 1.0f) * (0.5f * (float)(H - 1));

        const float fx0 = floorf(ix);
        const float fy0 = floorf(iy);
        const int x0 = (int)fx0, y0 = (int)fy0;
        const int y1 = y0 + 1;
        const float wx = ix - fx0;
        const float wy = iy - fy0;

        // x-pair: load (xa, xa+1); both x-taps live in this window with
        // boundary cases folded into (ux, uy):
        const int   xa   = min(max(x0, 0), W - 2);
        const float wx0v = (1.0f - wx) * ((x0 >= 0 && x0 < W) ? 1.0f : 0.0f);
        const float wx1v = wx * ((x0 + 1 >= 0 && x0 + 1 < W) ? 1.0f : 0.0f);
        // interior: (wx0v, wx1v); x0==-1: taps shift left -> (wx1v, 0);
        // x0==W-1: taps shift right -> (0, wx0v); fully OOB collapses to 0.
        const float ux = (x0 < 0) ? wx1v : ((x0 > W - 2) ? 0.0f : wx0v);
        const float uy = (x0 < 0) ? 0.0f : ((x0 > W - 2) ? wx0v : wx1v);

        const int yc0 = min(max(y0, 0), H - 1);
        const int yc1 = min(max(y1, 0), H - 1);
        const float wyv0 = (1.0f - wy) * ((y0 >= 0 && y0 < H) ? 1.0f : 0.0f);
        const float wyv1 = wy * ((y1 >= 0 && y1 < H) ? 1.0f : 0.0f);

        u0x[n] = ux * wyv0;  u0y[n] = uy * wyv0;
        u1x[n] = ux * wyv1;  u1y[n] = uy * wyv1;
        voff0[n] = yc0 * W + xa;
        voff1[n] = yc1 * W + xa;

        basep[n] = x + ((size_t)(b * N + n) * C + (size_t)(wv * CPW)) * HW;
    }

    // ---- gather: 2 channels per step -> 16 named pair-loads in flight ----
    float f[N][CPW];
#pragma unroll
    for (int cp = 0; cp < CPW / 2; ++cp) {
        const int c0 = 2 * cp, c1 = 2 * cp + 1;
        // channel c0 loads (8 pair-loads, named)
        f2v p00, p01, p02, p03, p04, p05, p06, p07;
        // channel c1 loads (8 pair-loads, named)
        f2v p10, p11, p12, p13, p14, p15, p16, p17;
        {
            const float* q0 = basep[0] + (size_t)c0 * HW;
            const float* q1 = basep[1] + (size_t)c0 * HW;
            const float* q2 = basep[2] + (size_t)c0 * HW;
            const float* q3 = basep[3] + (size_t)c0 * HW;
            p00 = *(const f2v*)(q0 + voff0[0]);
            p01 = *(const f2v*)(q0 + voff1[0]);
            p02 = *(const f2v*)(q1 + voff0[1]);
            p03 = *(const f2v*)(q1 + voff1[1]);
            p04 = *(const f2v*)(q2 + voff0[2]);
            p05 = *(const f2v*)(q2 + voff1[2]);
            p06 = *(const f2v*)(q3 + voff0[3]);
            p07 = *(const f2v*)(q3 + voff1[3]);
            const float* r0 = q0 + HW;
            const float* r1 = q1 + HW;
            const float* r2 = q2 + HW;
            const float* r3 = q3 + HW;
            p10 = *(const f2v*)(r0 + voff0[0]);
            p11 = *(const f2v*)(r0 + voff1[0]);
            p12 = *(const f2v*)(r1 + voff0[1]);
            p13 = *(const f2v*)(r1 + voff1[1]);
            p14 = *(const f2v*)(r2 + voff0[2]);
            p15 = *(const f2v*)(r2 + voff1[2]);
            p16 = *(const f2v*)(r3 + voff0[3]);
            p17 = *(const f2v*)(r3 + voff1[3]);
        }
        f[0][c0] = u0x[0] * p00.x + u0y[0] * p00.y + u1x[0] * p01.x + u1y[0] * p01.y;
        f[1][c0] = u0x[1] * p02.x + u0y[1] * p02.y + u1x[1] * p03.x + u1y[1] * p03.y;
        f[2][c0] = u0x[2] * p04.x + u0y[2] * p04.y + u1x[2] * p05.x + u1y[2] * p05.y;
        f[3][c0] = u0x[3] * p06.x + u0y[3] * p06.y + u1x[3] * p07.x + u1y[3] * p07.y;
        f[0][c1] = u0x[0] * p10.x + u0y[0] * p10.y + u1x[0] * p11.x + u1y[0] * p11.y;
        f[1][c1] = u0x[1] * p12.x + u0y[1] * p12.y + u1x[1] * p13.x + u1y[1] * p13.y;
        f[2][c1] = u0x[2] * p14.x + u0y[2] * p14.y + u1x[2] * p15.x + u1y[2] * p15.y;
        f[3][c1] = u0x[3] * p16.x + u0y[3] * p16.y + u1x[3] * p17.x + u1y[3] * p17.y;
    }

    // ---- partial scores over this wave's channels ----
    float s[N] = {0.f, 0.f, 0.f, 0.f};
#pragma unroll
    for (int cc = 0; cc < CPW; ++cc) {
        const float q = f[0][cc];
#pragma unroll
        for (int n = 0; n < N; ++n) s[n] += q * f[n][cc];
    }

    // ---- cross-wave reduction via LDS (lane-stride-1, conflict-free) ----
#pragma unroll
    for (int n = 0; n < N; ++n) sred[wv][n][lane] = s[n];
    __syncthreads();

    float st[N];
#pragma unroll
    for (int n = 0; n < N; ++n) {
        float acc = 0.f;
#pragma unroll
        for (int v = 0; v < WAVES; ++v) acc += sred[v][n][lane];
        st[n] = acc;
    }

    const float scale = 0.125f;  // 1/sqrt(64)
    const float s0 = st[0] * scale, s1 = st[1] * scale;
    const float s2 = st[2] * scale, s3 = st[3] * scale;
    const float m  = fmaxf(fmaxf(s0, s1), fmaxf(s2, s3));
    const float e0 = expf(s0 - m);
    const float e1 = expf(s1 - m);
    const float e2 = expf(s2 - m);
    const float e3 = expf(s3 - m);
    const float inv = 1.0f / (e0 + e1 + e2 + e3);
    const float attn[N] = {e0 * inv, e1 * inv, e2 * inv, e3 * inv};

    // ---- context from registers + coalesced store ----
    float* op = out + ((size_t)b * C + (size_t)(wv * CPW)) * HW
                    + (size_t)h * W + (size_t)w;
#pragma unroll
    for (int cc = 0; cc < CPW; ++cc) {
        float ctx = 0.f;
#pragma unroll
        for (int n = 0; n < N; ++n) ctx += attn[n] * f[n][cc];
        op[(size_t)cc * HW] = ctx;
    }
}

extern "C" void kernel_launch(void* const* d_in, const int* in_sizes, int n_in,
                              void* d_out, int out_size, void* d_ws, size_t ws_size,
                              hipStream_t stream) {
    const float* x  = (const float*)d_in[0];
    const float* P  = (const float*)d_in[1];
    float* out = (float*)d_out;

    dim3 block(512, 1, 1);
    dim3 grid(NWG, 1, 1);  // 2048 blocks, 1D, XCD-swizzled in-kernel
    hipLaunchKernelGGL(atten_comm_kernel, grid, block, 0, stream, x, P, out);
}